// Round 8
// baseline (304.264 us; speedup 1.0000x reference)
//
#include <hip/hip_runtime.h>
#include <hip/hip_bf16.h>
#include <stdint.h>

#define NPTS 131072
#define DIM  512
#define KC   512
#define BM   64
#define NKT  16          // DIM / 32 (BK = 32)

typedef float f32x16 __attribute__((ext_vector_type(16)));
typedef float f32x4  __attribute__((ext_vector_type(4)));
typedef short bf16x8 __attribute__((ext_vector_type(8)));

__device__ __forceinline__ float sq4(f32x4 a) {
  return a.x*a.x + a.y*a.y + a.z*a.z + a.w*a.w;
}

// packed RNE fp32->bf16 (v_cvt_pk_bf16_f32)
__device__ __forceinline__ bf16x8 pack8c(f32x4 a, f32x4 b) {
  bf16x8 r;
  float v[8] = {a.x, a.y, a.z, a.w, b.x, b.y, b.z, b.w};
  #pragma unroll
  for (int i = 0; i < 4; ++i) {
    __hip_bfloat162 t = __float22bfloat162_rn(make_float2(v[2*i], v[2*i+1]));
    union { __hip_bfloat162 h; short s[2]; } u; u.h = t;
    r[2*i]   = u.s[0];
    r[2*i+1] = u.s[1];
  }
  return r;
}

// scalar RNE (pre-kernel only)
__device__ __forceinline__ short f2bf(float f) {
  union { float f; unsigned u; } v; v.f = f;
  unsigned r = v.u + 0x7FFFu + ((v.u >> 16) & 1u);
  return (short)(r >> 16);
}
__device__ __forceinline__ bf16x8 pack8(f32x4 a, f32x4 b) {
  bf16x8 p;
  p[0] = f2bf(a.x); p[1] = f2bf(a.y); p[2] = f2bf(a.z); p[3] = f2bf(a.w);
  p[4] = f2bf(b.x); p[5] = f2bf(b.y); p[6] = f2bf(b.z); p[7] = f2bf(b.w);
  return p;
}

// ---------------------------------------------------------------------------
// Pre-kernel (identical layout to R5): clusters fp32 [512][512] -> bf16 in
// MFMA-fragment order: short offset = kt*16384 + s*8192 + wn*2048 + nt*512 +
// (h*32+r)*8 holding B[n=wn*128+nt*32+r][k=kt*32+s*16+h*8+j]. Main kernel
// reads fragments straight to registers (contiguous 1 KB per wave-instr,
// L2-resident 512 KB). Also c2[n] = ||c_n||^2 (fp32).
// ---------------------------------------------------------------------------
__global__ void dec_pack(const float* __restrict__ C, short* __restrict__ Bp,
                         float* __restrict__ c2) {
  const int n    = blockIdx.x;
  const int lane = threadIdx.x;
  const float* src = C + (size_t)n * DIM + lane * 8;
  f32x4 v0 = *(const f32x4*)src;
  f32x4 v1 = *(const f32x4*)(src + 4);
  float s = sq4(v0) + sq4(v1);
  #pragma unroll
  for (int m = 1; m < 64; m <<= 1) s += __shfl_xor(s, m, 64);
  if (lane == 0) c2[n] = s;
  const int kt = lane >> 2;
  const int st = (lane >> 1) & 1;
  const int hh = lane & 1;
  const int wn = n >> 7, nt = (n >> 5) & 3, r = n & 31;
  const size_t slot =
      (((size_t)(kt * 2 + st) * 4 + wn) * 4 + nt) * 64 + hh * 32 + r;
  *(bf16x8*)(Bp + slot * 8) = pack8(v0, v1);
}

// ---------------------------------------------------------------------------
// Main fused kernel — NO barriers in the K loop; waves fully autonomous.
// 512 threads = 8 waves (wm = wave>>2, wn = wave&3); block tile 64 x 512.
// Wave tile 32x128, 8 x mfma_f32_32x32x16_bf16 per kt (BK=32).
//
// A path (the R8 change): wave-private 2-slot LDS ring, REGISTER-staged:
//   iter kt: [issue A(kt+3) global->reg, coalesced: lane covers row
//   (l>>3)+8j, chunk (l&7)*4 floats — 8 rows x 128B contiguous per instr,
//   every sector touched once]  ->  [ds_write A(kt+1) from regs loaded 2
//   iters ago (fp32, 16B-chunk XOR swizzle c^=(row&7); x2 accumulated in
//   exact fp32)]  ->  [ds_read_b128 frags of A(kt) (swizzled, conflict-free)
//   -> cvt_pk -> 8 MFMA with B(kt) regs].
//   Same-wave DS ops are ordered; global->reg deps get precise counted
//   vmcnt from the compiler. No __syncthreads anywhere in the loop.
// B path: fragment loads straight from pre-packed L2-resident Bp,
//   prefetched one iteration ahead into the alternate register set.
// Epilogue: x2 butterfly (masks 1,2,4) + shfl pickup; q = rcp(1+d2);
// row-sum butterflies; ONE barrier to combine wn partials; normalize; store.
// ---------------------------------------------------------------------------
__global__ __launch_bounds__(512, 2)
void dec_main(const float* __restrict__ X, const short* __restrict__ Bp,
              const float* __restrict__ c2g, float* __restrict__ out) {
  __shared__ float Apriv[8][2][1024];   // 8 waves x 2 slots x 4 KB
  __shared__ float part[4][BM];
  __shared__ float rowinv[BM];

  const int tid  = threadIdx.x;
  const int lane = tid & 63;
  const int wave = tid >> 6;
  const int wm   = wave >> 2;   // 0..1 : row half
  const int wn   = wave & 3;    // 0..3 : column quarter
  const int l31  = lane & 31;
  const int h    = lane >> 5;
  const int row0 = blockIdx.x * BM;

  // A global base: lane covers rows wm*32 + (l>>3) + 8j, floats (l&7)*4..+3
  const float* aptr =
      X + (size_t)(row0 + wm * 32 + (lane >> 3)) * DIM + (lane & 7) * 4;
  // A LDS write offset (floats): row (l>>3)+8j, swizzled chunk (l&7)^(l>>3)
  const int awoff = (lane >> 3) * 32 + (((lane & 7) ^ (lane >> 3)) << 2);
  // A LDS read offsets (floats): row l31, chunks (s*4+h*2+i) ^ (l31&7)
  int rdo[2][2];
  #pragma unroll
  for (int s = 0; s < 2; ++s)
    #pragma unroll
    for (int i = 0; i < 2; ++i)
      rdo[s][i] = l31 * 32 + (((s * 4 + h * 2 + i) ^ (l31 & 7)) << 2);

  // B fragment base (shorts): + kt*16384 + s*8192 + nt*512
  const short* bB = Bp + wn * 2048 + lane * 8;

  f32x16 acc[4];
  #pragma unroll
  for (int nt = 0; nt < 4; ++nt) acc[nt] = (f32x16)0.f;
  float x2s[4] = {0.f, 0.f, 0.f, 0.f};

  f32x4  aS[3][4];      // A register pipeline: aS[k%3] holds A(k), k=kt+1..kt+3
  bf16x8 bS[2][2][4];   // B ping-pong: bS[k%2][s][nt]

  // ---- prologue ----
  {
    f32x4 a0[4];
    #pragma unroll
    for (int j = 0; j < 4; ++j)
      a0[j] = *(const f32x4*)(aptr + j * (8 * DIM));
    #pragma unroll
    for (int j = 0; j < 4; ++j) {
      x2s[j] += sq4(a0[j]);
      *(f32x4*)(&Apriv[wave][0][0] + awoff + j * 256) = a0[j];
    }
  }
  #pragma unroll
  for (int k = 1; k <= 2; ++k)
    #pragma unroll
    for (int j = 0; j < 4; ++j)
      aS[k % 3][j] = *(const f32x4*)(aptr + k * 32 + j * (8 * DIM));
  #pragma unroll
  for (int s = 0; s < 2; ++s)
    #pragma unroll
    for (int nt = 0; nt < 4; ++nt)
      bS[0][s][nt] = *(const bf16x8*)(bB + s * 8192 + nt * 512);

  // ---- barrier-free K loop (fully unrolled; all set indices static) ----
  #pragma unroll
  for (int kt = 0; kt < NKT; ++kt) {
    // (1) issue A(kt+3) -> regs (3-iteration latency window)
    const int kpre = (kt + 3 < NKT) ? kt + 3 : NKT - 1;
    #pragma unroll
    for (int j = 0; j < 4; ++j)
      aS[(kt + 3) % 3][j] =
          *(const f32x4*)(aptr + kpre * 32 + j * (8 * DIM));

    // (2) issue B(kt+1) -> regs (1-iteration window, L2-resident)
    const int kb = (kt + 1 < NKT) ? kt + 1 : NKT - 1;
    #pragma unroll
    for (int s = 0; s < 2; ++s)
      #pragma unroll
      for (int nt = 0; nt < 4; ++nt)
        bS[(kt + 1) & 1][s][nt] =
            *(const bf16x8*)(bB + kb * 16384 + s * 8192 + nt * 512);

    // (3) ds_write A(kt+1) from regs loaded 2 iterations ago; fuse x2
    if (kt + 1 < NKT) {
      float* dst = &Apriv[wave][(kt + 1) & 1][0];
      #pragma unroll
      for (int j = 0; j < 4; ++j) {
        x2s[j] += sq4(aS[(kt + 1) % 3][j]);
        *(f32x4*)(dst + awoff + j * 256) = aS[(kt + 1) % 3][j];
      }
    }

    // (4) ds_read A(kt) frags (conflict-free), cvt, 8 MFMA with B(kt)
    {
      const float* src = &Apriv[wave][kt & 1][0];
      #pragma unroll
      for (int s = 0; s < 2; ++s) {
        f32x4 lo = *(const f32x4*)(src + rdo[s][0]);
        f32x4 hi = *(const f32x4*)(src + rdo[s][1]);
        bf16x8 af = pack8c(lo, hi);
        #pragma unroll
        for (int nt = 0; nt < 4; ++nt)
          acc[nt] = __builtin_amdgcn_mfma_f32_32x32x16_bf16(
              af, bS[kt & 1][s][nt], acc[nt], 0, 0, 0);
      }
    }
  }

  // ---- x2: reduce over the 8 chunk-lanes of each row group ----
  #pragma unroll
  for (int j = 0; j < 4; ++j) {
    x2s[j] += __shfl_xor(x2s[j], 1, 64);
    x2s[j] += __shfl_xor(x2s[j], 2, 64);
    x2s[j] += __shfl_xor(x2s[j], 4, 64);
  }
  // x2 of local row r lives in lane-group (r&7) (lanes (r&7)*8..+7), reg r>>3

  float c2v[4];
  #pragma unroll
  for (int nt = 0; nt < 4; ++nt) c2v[nt] = c2g[wn * 128 + nt * 32 + l31];

  // ---- q = rcp(1+d2), per-row partial sums over this wave's 128 cols ----
  float srow[16];
  #pragma unroll
  for (int r = 0; r < 16; ++r) {
    // local row = (r&3) + 8*(r>>2) + 4*h ; reg j = r>>2 ; group = (r&3)+4*h
    const float x2m = __shfl(x2s[r >> 2], ((r & 3) + 4 * h) * 8, 64);
    float s = 0.f;
    #pragma unroll
    for (int nt = 0; nt < 4; ++nt) {
      float d2 = fmaxf(x2m + c2v[nt] - 2.f * acc[nt][r], 0.f);
      float q = __builtin_amdgcn_rcpf(1.f + d2);
      acc[nt][r] = q;
      s += q;
    }
    #pragma unroll
    for (int msk = 1; msk < 32; msk <<= 1) s += __shfl_xor(s, msk, 64);
    srow[r] = s;
  }

  if (l31 == 0) {
    #pragma unroll
    for (int r = 0; r < 16; ++r)
      part[wn][wm * 32 + (r & 3) + 8 * (r >> 2) + 4 * h] = srow[r];
  }
  __syncthreads();
  if (tid < BM)
    rowinv[tid] = __builtin_amdgcn_rcpf(part[0][tid] + part[1][tid] +
                                        part[2][tid] + part[3][tid]);
  __syncthreads();

  // ---- normalize + coalesced stores ----
  #pragma unroll
  for (int r = 0; r < 16; ++r) {
    const int row = wm * 32 + (r & 3) + 8 * (r >> 2) + 4 * h;
    const float iv = rowinv[row];
    float* o = out + (size_t)(row0 + row) * KC + wn * 128 + l31;
    #pragma unroll
    for (int nt = 0; nt < 4; ++nt)
      o[nt * 32] = acc[nt][r] * iv;
  }
}

extern "C" void kernel_launch(void* const* d_in, const int* in_sizes, int n_in,
                              void* d_out, int out_size, void* d_ws, size_t ws_size,
                              hipStream_t stream) {
  const float* X = (const float*)d_in[0];   // inputs  [131072, 512] fp32
  const float* C = (const float*)d_in[1];   // clusters [512, 512] fp32
  float* out = (float*)d_out;               // [131072, 512] fp32

  short* Bp = (short*)d_ws;                                   // 512 KB packed bf16 clusters
  float* c2 = (float*)((char*)d_ws + (size_t)KC * DIM * 2);   // 2 KB cluster norms

  dec_pack<<<KC, 64, 0, stream>>>(C, Bp, c2);
  dec_main<<<NPTS / BM, 512, 0, stream>>>(X, Bp, c2, out);
}

// Round 9
// 272.763 us; speedup vs baseline: 1.1155x; 1.1155x over previous
//
#include <hip/hip_runtime.h>
#include <hip/hip_bf16.h>
#include <stdint.h>

#define NPTS 131072
#define DIM  512
#define KC   512
#define BM   64
#define NKT  16          // DIM / 32 (BK = 32)

typedef float f32x16 __attribute__((ext_vector_type(16)));
typedef float f32x4  __attribute__((ext_vector_type(4)));
typedef short bf16x8 __attribute__((ext_vector_type(8)));

__device__ __forceinline__ float sq4(f32x4 a) {
  return a.x*a.x + a.y*a.y + a.z*a.z + a.w*a.w;
}

// packed RNE fp32->bf16 (v_cvt_pk_bf16_f32)
__device__ __forceinline__ bf16x8 pack8c(f32x4 a, f32x4 b) {
  bf16x8 r;
  float v[8] = {a.x, a.y, a.z, a.w, b.x, b.y, b.z, b.w};
  #pragma unroll
  for (int i = 0; i < 4; ++i) {
    __hip_bfloat162 t = __float22bfloat162_rn(make_float2(v[2*i], v[2*i+1]));
    union { __hip_bfloat162 h; short s[2]; } u; u.h = t;
    r[2*i]   = u.s[0];
    r[2*i+1] = u.s[1];
  }
  return r;
}

// scalar RNE (cluster pre-kernel only)
__device__ __forceinline__ short f2bf(float f) {
  union { float f; unsigned u; } v; v.f = f;
  unsigned r = v.u + 0x7FFFu + ((v.u >> 16) & 1u);
  return (short)(r >> 16);
}
__device__ __forceinline__ bf16x8 pack8(f32x4 a, f32x4 b) {
  bf16x8 p;
  p[0] = f2bf(a.x); p[1] = f2bf(a.y); p[2] = f2bf(a.z); p[3] = f2bf(a.w);
  p[4] = f2bf(b.x); p[5] = f2bf(b.y); p[6] = f2bf(b.z); p[7] = f2bf(b.w);
  return p;
}

// ---------------------------------------------------------------------------
// Cluster pre-kernel (layout verified R5-R8): fp32 [512][512] -> bf16 in
// MFMA-B-fragment order: short offset = kt*16384 + s*8192 + wn*2048 +
// nt*512 + (h*32+r)*8 holding B[n=wn*128+nt*32+r][k=kt*32+s*16+h*8+j].
// Also c2[n] = ||c_n||^2 (fp32).
// ---------------------------------------------------------------------------
__global__ void dec_pack(const float* __restrict__ C, short* __restrict__ Bp,
                         float* __restrict__ c2) {
  const int n    = blockIdx.x;
  const int lane = threadIdx.x;
  const float* src = C + (size_t)n * DIM + lane * 8;
  f32x4 v0 = *(const f32x4*)src;
  f32x4 v1 = *(const f32x4*)(src + 4);
  float s = sq4(v0) + sq4(v1);
  #pragma unroll
  for (int m = 1; m < 64; m <<= 1) s += __shfl_xor(s, m, 64);
  if (lane == 0) c2[n] = s;
  const int kt = lane >> 2;
  const int st = (lane >> 1) & 1;
  const int hh = lane & 1;
  const int wn = n >> 7, nt = (n >> 5) & 3, r = n & 31;
  const size_t slot =
      (((size_t)(kt * 2 + st) * 4 + wn) * 4 + nt) * 64 + hh * 32 + r;
  *(bf16x8*)(Bp + slot * 8) = pack8(v0, v1);
}

// ---------------------------------------------------------------------------
// Pass 1: X fp32 [131072][512] -> Xp bf16 in MFMA-A-fragment order +
// x2g[row] = ||x_row||^2 (exact fp32).
// Layout: Xp[(g*32 + ks)*512 + lane*8 .. +7] holds X[g*32+r][ks*16+h*8+j]
// for lane = h*32+r — i.e. each (g,ks) slab is the literal 1 KB A-fragment
// the GEMM wave loads with one dwordx4 per lane.
// Reads: lane reads 32 B contiguous of its row; the h-pair covers a full
// 64 B sector -> every sector fetched exactly once (sector-perfect).
// Writes: base + lane*16 -> contiguous 1 KB per store instruction.
// One wave per 32-row group; 4096 groups; 1024 blocks x 256 threads.
// ---------------------------------------------------------------------------
__global__ __launch_bounds__(256)
void dec_packx(const float* __restrict__ X, short* __restrict__ Xp,
               float* __restrict__ x2g) {
  const int g    = blockIdx.x * 4 + (threadIdx.x >> 6);
  const int lane = threadIdx.x & 63;
  const int h    = lane >> 5;
  const int r    = lane & 31;
  const float* src = X + (size_t)(g * 32 + r) * DIM + h * 8;
  short* dst = Xp + (size_t)g * 16384 + lane * 8;
  float x2 = 0.f;
  #pragma unroll 4
  for (int ks = 0; ks < 32; ++ks) {
    f32x4 lo = *(const f32x4*)(src + ks * 16);
    f32x4 hi = *(const f32x4*)(src + ks * 16 + 4);
    x2 += sq4(lo) + sq4(hi);
    *(bf16x8*)(dst + ks * 512) = pack8c(lo, hi);
  }
  x2 += __shfl_xor(x2, 32, 64);       // combine the two k-halves of the row
  if (lane < 32) x2g[g * 32 + r] = x2;
}

// ---------------------------------------------------------------------------
// Pass 2: pure fragment-fed GEMM + fused epilogue.
// 512 threads = 8 waves (wm = wave>>2, wn = wave&3); block tile 64 x 512
// (full cluster width -> block-local normalization). Wave tile 32x128 via
// 8 x mfma_f32_32x32x16_bf16 per kt.
// Inner loop per wave: 8 B-frag loads (contiguous 1 KB, L2-resident) +
// 2 A-frag loads for kt+1 (contiguous 1 KB, HBM stream, ping-pong) +
// 8 MFMA. NO LDS, NO barriers, NO cvt, NO x2 — nothing else.
// B is issued before the A-prefetch so the in-order vmcnt queue retires
// [B(kt), A(kt+1)]: waiting on B(kt) never waits on fresh HBM loads, and
// A(kt+1) has a full iteration + TLP (16 waves/CU at ~120 regs) to land.
// Epilogue: x2/c2 from precomputed arrays; q = rcp(1+d2); butterfly
// row-sums; one barrier; normalize; coalesced stores.
// ---------------------------------------------------------------------------
__global__ __launch_bounds__(512)
void dec_main2(const short* __restrict__ Xp, const short* __restrict__ Bp,
               const float* __restrict__ c2g, const float* __restrict__ x2g,
               float* __restrict__ out) {
  __shared__ float part[4][BM];
  __shared__ float rowinv[BM];

  const int tid  = threadIdx.x;
  const int lane = tid & 63;
  const int wave = tid >> 6;
  const int wm   = wave >> 2;   // 0..1 : row half
  const int wn   = wave & 3;    // 0..3 : column quarter
  const int l31  = lane & 31;
  const int h    = lane >> 5;
  const int row0 = blockIdx.x * BM;
  const int g    = blockIdx.x * 2 + wm;     // 32-row group

  const short* aB = Xp + (size_t)g * 16384 + lane * 8;   // + kt*1024 + s*512
  const short* bB = Bp + wn * 2048 + lane * 8;           // + kt*16384 + s*8192 + nt*512

  f32x16 acc[4];
  #pragma unroll
  for (int nt = 0; nt < 4; ++nt) acc[nt] = (f32x16)0.f;

  bf16x8 aF[2][2];              // ping-pong A fragments [kt&1][s]
  #pragma unroll
  for (int s = 0; s < 2; ++s)
    aF[0][s] = *(const bf16x8*)(aB + s * 512);

  #pragma unroll
  for (int kt = 0; kt < NKT; ++kt) {
    // (1) B fragments for this kt (L2-resident; oldest in queue)
    bf16x8 bF[2][4];
    #pragma unroll
    for (int s = 0; s < 2; ++s)
      #pragma unroll
      for (int nt = 0; nt < 4; ++nt)
        bF[s][nt] = *(const bf16x8*)(bB + kt * 16384 + s * 8192 + nt * 512);

    // (2) A prefetch for kt+1 (HBM; consumed next iteration)
    if (kt + 1 < NKT) {
      #pragma unroll
      for (int s = 0; s < 2; ++s)
        aF[(kt + 1) & 1][s] =
            *(const bf16x8*)(aB + (kt + 1) * 1024 + s * 512);
    }

    // (3) 8 MFMA
    #pragma unroll
    for (int s = 0; s < 2; ++s)
      #pragma unroll
      for (int nt = 0; nt < 4; ++nt)
        acc[nt] = __builtin_amdgcn_mfma_f32_32x32x16_bf16(
            aF[kt & 1][s], bF[s][nt], acc[nt], 0, 0, 0);
  }

  // ---- epilogue ----
  const float x2v = x2g[row0 + wm * 32 + l31];   // both h-halves load row l31
  float c2v[4];
  #pragma unroll
  for (int nt = 0; nt < 4; ++nt) c2v[nt] = c2g[wn * 128 + nt * 32 + l31];

  float srow[16];
  #pragma unroll
  for (int r = 0; r < 16; ++r) {
    const int mloc = (r & 3) + 8 * (r >> 2) + 4 * h;   // 0..31
    const float x2m = __shfl(x2v, mloc, 64);
    float s = 0.f;
    #pragma unroll
    for (int nt = 0; nt < 4; ++nt) {
      float d2 = fmaxf(x2m + c2v[nt] - 2.f * acc[nt][r], 0.f);
      float q = __builtin_amdgcn_rcpf(1.f + d2);
      acc[nt][r] = q;
      s += q;
    }
    #pragma unroll
    for (int msk = 1; msk < 32; msk <<= 1) s += __shfl_xor(s, msk, 64);
    srow[r] = s;
  }

  if (l31 == 0) {
    #pragma unroll
    for (int r = 0; r < 16; ++r)
      part[wn][wm * 32 + (r & 3) + 8 * (r >> 2) + 4 * h] = srow[r];
  }
  __syncthreads();
  if (tid < BM)
    rowinv[tid] = __builtin_amdgcn_rcpf(part[0][tid] + part[1][tid] +
                                        part[2][tid] + part[3][tid]);
  __syncthreads();

  #pragma unroll
  for (int r = 0; r < 16; ++r) {
    const int row = wm * 32 + (r & 3) + 8 * (r >> 2) + 4 * h;
    const float iv = rowinv[row];
    float* o = out + (size_t)(row0 + row) * KC + wn * 128 + l31;
    #pragma unroll
    for (int nt = 0; nt < 4; ++nt)
      o[nt * 32] = acc[nt][r] * iv;
  }
}

// ---------------------------------------------------------------------------
// Fallback (verified R5 single-pass, 177 us) — used only if ws_size is too
// small for the 128 MB Xp buffer.
// ---------------------------------------------------------------------------
typedef short bf16x4 __attribute__((ext_vector_type(4)));
__device__ __forceinline__ bf16x4 pack4(f32x4 a) {
  bf16x4 p;
  p[0] = f2bf(a.x); p[1] = f2bf(a.y); p[2] = f2bf(a.z); p[3] = f2bf(a.w);
  return p;
}
__device__ __forceinline__ void gload_lds16(const short* g, short* l) {
  __builtin_amdgcn_global_load_lds(
      (const __attribute__((address_space(1))) unsigned int*)g,
      (__attribute__((address_space(3))) unsigned int*)l, 16, 0, 0);
}

__global__ __launch_bounds__(512, 4)
void dec_main_fb(const float* __restrict__ X, const short* __restrict__ Bp,
                 const float* __restrict__ c2g, float* __restrict__ out) {
  __shared__ short Bbuf[2][KC * 32];
  __shared__ short Abuf[2][2 * 2 * BM * 8];
  __shared__ float x2sh[BM];
  __shared__ float part[4][BM];
  __shared__ float rowinv[BM];

  const int tid  = threadIdx.x;
  const int lane = tid & 63;
  const int wave = tid >> 6;
  const int wm   = wave >> 2;
  const int wn   = wave & 3;
  const int l31  = lane & 31;
  const int h    = lane >> 5;
  const int row0 = blockIdx.x * BM;

  const int arow = tid >> 3;
  const int ac   = tid & 7;
  const float* aptr = X + (size_t)(row0 + arow) * DIM + ac * 4;
  const int awoff = (((ac >> 2) * 2 + ((ac >> 1) & 1)) * BM + arow) * 8 +
                    (ac & 1) * 4;
  const short* bsrc = Bp + tid * 8;

  f32x16 acc[4];
  #pragma unroll
  for (int nt = 0; nt < 4; ++nt) acc[nt] = (f32x16)0.f;
  float x2a = 0.f;

  {
    #pragma unroll
    for (int sw = 0; sw < 4; ++sw)
      gload_lds16(bsrc + sw * 4096, &Bbuf[0][sw * 4096 + tid * 8]);
    f32x4 a0 = *(const f32x4*)(aptr);
    x2a += sq4(a0);
    *(bf16x4*)&Abuf[0][awoff] = pack4(a0);
  }
  f32x4 av_w = *(const f32x4*)(aptr + 32);
  f32x4 av_p = *(const f32x4*)(aptr + 64);
  __syncthreads();

  for (int kt = 0; kt < NKT; ++kt) {
    const int cur = kt & 1, nxt = cur ^ 1;
    if (kt + 1 < NKT) {
      const int kpre = (kt + 3 < NKT) ? (kt + 3) : (NKT - 1);
      f32x4 av_n = *(const f32x4*)(aptr + kpre * 32);
      #pragma unroll
      for (int sw = 0; sw < 4; ++sw)
        gload_lds16(bsrc + (size_t)(kt + 1) * 16384 + sw * 4096,
                    &Bbuf[nxt][sw * 4096 + tid * 8]);
      x2a += sq4(av_w);
      *(bf16x4*)&Abuf[nxt][awoff] = pack4(av_w);
      av_w = av_p;
      av_p = av_n;
    }
    #pragma unroll
    for (int s = 0; s < 2; ++s) {
      bf16x8 af = *(const bf16x8*)
          &Abuf[cur][((s * 2 + h) * BM + wm * 32 + l31) * 8];
      bf16x8 bfr[4];
      #pragma unroll
      for (int nt = 0; nt < 4; ++nt)
        bfr[nt] = *(const bf16x8*)
            &Bbuf[cur][((s * 4 + wn) * 4 + nt) * 512 + lane * 8];
      #pragma unroll
      for (int nt = 0; nt < 4; ++nt)
        acc[nt] = __builtin_amdgcn_mfma_f32_32x32x16_bf16(
            af, bfr[nt], acc[nt], 0, 0, 0);
    }
    __syncthreads();
  }

  x2a += __shfl_xor(x2a, 1, 64);
  x2a += __shfl_xor(x2a, 2, 64);
  x2a += __shfl_xor(x2a, 4, 64);
  if ((tid & 7) == 0) x2sh[arow] = x2a;
  __syncthreads();

  float c2v[4];
  #pragma unroll
  for (int nt = 0; nt < 4; ++nt) c2v[nt] = c2g[wn * 128 + nt * 32 + l31];

  float srow[16];
  #pragma unroll
  for (int r = 0; r < 16; ++r) {
    const int mloc = (r & 3) + 8 * (r >> 2) + 4 * h;
    const float x2m = x2sh[wm * 32 + mloc];
    float s = 0.f;
    #pragma unroll
    for (int nt = 0; nt < 4; ++nt) {
      float d2 = fmaxf(x2m + c2v[nt] - 2.f * acc[nt][r], 0.f);
      float q = __builtin_amdgcn_rcpf(1.f + d2);
      acc[nt][r] = q;
      s += q;
    }
    #pragma unroll
    for (int msk = 1; msk < 32; msk <<= 1) s += __shfl_xor(s, msk, 64);
    srow[r] = s;
  }
  if (l31 == 0) {
    #pragma unroll
    for (int r = 0; r < 16; ++r)
      part[wn][wm * 32 + (r & 3) + 8 * (r >> 2) + 4 * h] = srow[r];
  }
  __syncthreads();
  if (tid < BM)
    rowinv[tid] = __builtin_amdgcn_rcpf(part[0][tid] + part[1][tid] +
                                        part[2][tid] + part[3][tid]);
  __syncthreads();
  #pragma unroll
  for (int r = 0; r < 16; ++r) {
    const int row = wm * 32 + (r & 3) + 8 * (r >> 2) + 4 * h;
    const float iv = rowinv[row];
    float* o = out + (size_t)(row0 + row) * KC + wn * 128 + l31;
    #pragma unroll
    for (int nt = 0; nt < 4; ++nt)
      o[nt * 32] = acc[nt][r] * iv;
  }
}

extern "C" void kernel_launch(void* const* d_in, const int* in_sizes, int n_in,
                              void* d_out, int out_size, void* d_ws, size_t ws_size,
                              hipStream_t stream) {
  const float* X = (const float*)d_in[0];   // inputs  [131072, 512] fp32
  const float* C = (const float*)d_in[1];   // clusters [512, 512] fp32
  float* out = (float*)d_out;               // [131072, 512] fp32

  // ws layout: [Bp 512 KB][c2 2 KB][x2g 512 KB][pad][Xp 128 MB @ 1.25 MB]
  char* ws = (char*)d_ws;
  short* Bp  = (short*)ws;
  float* c2  = (float*)(ws + (size_t)KC * DIM * 2);            // 512 KB
  float* x2g = (float*)(ws + (size_t)KC * DIM * 2 + 4096);
  short* Xp  = (short*)(ws + (1u << 21));                      // 2 MB offset
  const size_t REQ = (1u << 21) + (size_t)NPTS * DIM * 2;      // ~130 MB

  dec_pack<<<KC, 64, 0, stream>>>(C, Bp, c2);
  if (ws_size >= REQ) {
    dec_packx<<<NPTS / 128, 256, 0, stream>>>(X, Xp, x2g);
    dec_main2<<<NPTS / BM, 512, 0, stream>>>(Xp, Bp, c2, x2g, out);
  } else {
    dec_main_fb<<<NPTS / BM, 512, 0, stream>>>(X, Bp, c2, out);
  }
}

// Round 10
// 227.864 us; speedup vs baseline: 1.3353x; 1.1970x over previous
//
#include <hip/hip_runtime.h>
#include <hip/hip_bf16.h>
#include <stdint.h>

#define NPTS 131072
#define DIM  512
#define KC   512
#define BM   64
#define BK   32
#define NKT  16          // DIM / BK

typedef float f32x16 __attribute__((ext_vector_type(16)));
typedef float f32x4  __attribute__((ext_vector_type(4)));
typedef short bf16x8 __attribute__((ext_vector_type(8)));

__device__ __forceinline__ float sq4(f32x4 a) {
  return a.x*a.x + a.y*a.y + a.z*a.z + a.w*a.w;
}

// packed RNE fp32->bf16 (v_cvt_pk_bf16_f32)
__device__ __forceinline__ bf16x8 pack8c(f32x4 a, f32x4 b) {
  bf16x8 r;
  float v[8] = {a.x, a.y, a.z, a.w, b.x, b.y, b.z, b.w};
  #pragma unroll
  for (int i = 0; i < 4; ++i) {
    __hip_bfloat162 t = __float22bfloat162_rn(make_float2(v[2*i], v[2*i+1]));
    union { __hip_bfloat162 h; short s[2]; } u; u.h = t;
    r[2*i]   = u.s[0];
    r[2*i+1] = u.s[1];
  }
  return r;
}

// scalar RNE (cluster pre-kernel only)
__device__ __forceinline__ short f2bf(float f) {
  union { float f; unsigned u; } v; v.f = f;
  unsigned r = v.u + 0x7FFFu + ((v.u >> 16) & 1u);
  return (short)(r >> 16);
}
__device__ __forceinline__ bf16x8 pack8(f32x4 a, f32x4 b) {
  bf16x8 p;
  p[0] = f2bf(a.x); p[1] = f2bf(a.y); p[2] = f2bf(a.z); p[3] = f2bf(a.w);
  p[4] = f2bf(b.x); p[5] = f2bf(b.y); p[6] = f2bf(b.z); p[7] = f2bf(b.w);
  return p;
}

__device__ __forceinline__ void gload_lds16(const void* g, void* l) {
  __builtin_amdgcn_global_load_lds(
      (const __attribute__((address_space(1))) unsigned int*)g,
      (__attribute__((address_space(3))) unsigned int*)l, 16, 0, 0);
}

// ---------------------------------------------------------------------------
// Cluster pre-kernel (layout verified R5-R9): fp32 [512][512] -> bf16 in
// MFMA-B-fragment order: short offset = kt*16384 + (st*4+wn)*2048 + nt*512 +
// (h*32+r)*8 holding B[n=wn*128+nt*32+r][k=kt*32+st*16+h*8+j].
// Each 32 KB kt-tile contiguous -> staged linearly with global_load_lds;
// fragments read at base + lane*16 (conflict-free). c2[n] = ||c_n||^2 fp32.
// ---------------------------------------------------------------------------
__global__ void dec_pack(const float* __restrict__ C, short* __restrict__ Bp,
                         float* __restrict__ c2) {
  const int n    = blockIdx.x;
  const int lane = threadIdx.x;
  const float* src = C + (size_t)n * DIM + lane * 8;
  f32x4 v0 = *(const f32x4*)src;
  f32x4 v1 = *(const f32x4*)(src + 4);
  float s = sq4(v0) + sq4(v1);
  #pragma unroll
  for (int m = 1; m < 64; m <<= 1) s += __shfl_xor(s, m, 64);
  if (lane == 0) c2[n] = s;
  const int kt = lane >> 2;
  const int st = (lane >> 1) & 1;
  const int hh = lane & 1;
  const int wn = n >> 7, nt = (n >> 5) & 3, r = n & 31;
  const size_t slot =
      (((size_t)(kt * 2 + st) * 4 + wn) * 4 + nt) * 64 + hh * 32 + r;
  *(bf16x8*)(Bp + slot * 8) = pack8(v0, v1);
}

// ---------------------------------------------------------------------------
// Main fused kernel (R10): R5 structure with the A register-pipeline DELETED.
// 512 threads = 8 waves (wm = wave>>2, wn = wave&3); block tile 64 x 512
// (full cluster width -> block-local normalization). Wave tile 32x128 via
// 8 x mfma_f32_32x32x16_bf16 per kt (BK=32).
//
// The ONLY global memory ops in the K loop are global_load_lds (no register
// destinations) -> the compiler's vmcnt(0)+barrier drain meets loads issued
// at the TOP of the same iteration (~full compute phase old): m97 pattern.
//   per kt: stage B(kt+1) [4 x gload_lds16, pre-packed frag order, linear]
//           stage A(kt+1) [1 x gload_lds16, fp32, SOURCE-side XOR swizzle
//             (m173): thread t reads X[row0+(t>>3)][ ((t&7)^((t>>3)&7))*4
//             + kt*32 ..], dest linear t*16B]
//           compute kt: per s: 2 x ds_read_b128 fp32 A-frag (swizzled,
//             ~4-way), cvt_pk -> bf16 frag, 4 x ds_read_b128 B-frag
//             (linear), 4 MFMA; x2 accumulated from the fp32 frag regs
//           __syncthreads
// x2: each lane covers k-half h of row l31 -> one shfl_xor(32) completes it.
// LDS: 64 KB Bbuf + 16 KB Abuf = 80 KB exact -> 2 blocks/CU; epilogue
// scratch overlaid on Abuf (dead after the final barrier).
// ---------------------------------------------------------------------------
__global__ __launch_bounds__(512)
void dec_main(const float* __restrict__ X, const short* __restrict__ Bp,
              const float* __restrict__ c2g, float* __restrict__ out) {
  __shared__ short Bbuf[2][KC * BK];   // 2 x 32 KB
  __shared__ float Abuf[2][BM * BK];   // 2 x 8 KB (fp32 A tile, swizzled)

  const int tid  = threadIdx.x;
  const int lane = tid & 63;
  const int wave = tid >> 6;
  const int wm   = wave >> 2;   // 0..1 : row half
  const int wn   = wave & 3;    // 0..3 : column quarter
  const int l31  = lane & 31;
  const int h    = lane >> 5;
  const int row0 = blockIdx.x * BM;

  // A staging: thread t -> row (t>>3), source chunk ((t&7)^((t>>3)&7)),
  // dest linear t*4 floats. Covers the full 64x32 fp32 tile.
  const float* asrc = X + (size_t)(row0 + (tid >> 3)) * DIM +
                      (((tid & 7) ^ ((tid >> 3) & 7)) << 2);
  // B staging: 4 sweeps of 16 B/thread, linear (pre-packed source)
  const short* bsrc = Bp + tid * 8;

  // A fragment read offsets (floats): row (wm*32+l31), chunk (s*4+h*2+i)^(l31&7)
  const int arow = (wm * 32 + l31) * BK;

  f32x16 acc[4];
  #pragma unroll
  for (int nt = 0; nt < 4; ++nt) acc[nt] = (f32x16)0.f;
  float x2 = 0.f;

  // ---- prologue: stage kt=0 ----
  #pragma unroll
  for (int sw = 0; sw < 4; ++sw)
    gload_lds16(bsrc + sw * 4096, &Bbuf[0][sw * 4096 + tid * 8]);
  gload_lds16(asrc, &Abuf[0][tid * 4]);
  __syncthreads();

  // ---- K loop: one barrier per kt; no register-dest global loads ----
  for (int kt = 0; kt < NKT; ++kt) {
    const int cur = kt & 1, nxt = cur ^ 1;

    if (kt + 1 < NKT) {
      #pragma unroll
      for (int sw = 0; sw < 4; ++sw)
        gload_lds16(bsrc + (size_t)(kt + 1) * 16384 + sw * 4096,
                    &Bbuf[nxt][sw * 4096 + tid * 8]);
      gload_lds16(asrc + (kt + 1) * BK, &Abuf[nxt][tid * 4]);
    }

    #pragma unroll
    for (int s = 0; s < 2; ++s) {
      // A fragment: fp32, swizzled chunks, cvt -> bf16
      f32x4 lo = *(const f32x4*)
          &Abuf[cur][arow + (((s * 4 + h * 2 + 0) ^ (l31 & 7)) << 2)];
      f32x4 hi = *(const f32x4*)
          &Abuf[cur][arow + (((s * 4 + h * 2 + 1) ^ (l31 & 7)) << 2)];
      x2 += sq4(lo) + sq4(hi);
      bf16x8 af = pack8c(lo, hi);
      // B fragments: linear, conflict-free
      bf16x8 bfr[4];
      #pragma unroll
      for (int nt = 0; nt < 4; ++nt)
        bfr[nt] = *(const bf16x8*)
            &Bbuf[cur][((s * 4 + wn) * 4 + nt) * 512 + lane * 8];
      #pragma unroll
      for (int nt = 0; nt < 4; ++nt)
        acc[nt] = __builtin_amdgcn_mfma_f32_32x32x16_bf16(
            af, bfr[nt], acc[nt], 0, 0, 0);
    }

    __syncthreads();
  }

  // ---- x2: combine the two k-halves; lane l31 holds x2(row wm*32+l31) ----
  x2 += __shfl_xor(x2, 32, 64);

  float c2v[4];
  #pragma unroll
  for (int nt = 0; nt < 4; ++nt) c2v[nt] = c2g[wn * 128 + nt * 32 + l31];

  // ---- q = rcp(1+d2), per-row partial sums over this wave's 128 cols ----
  float srow[16];
  #pragma unroll
  for (int r = 0; r < 16; ++r) {
    const int mloc = (r & 3) + 8 * (r >> 2) + 4 * h;   // 0..31
    const float x2m = __shfl(x2, mloc, 64);
    float s = 0.f;
    #pragma unroll
    for (int nt = 0; nt < 4; ++nt) {
      float d2 = fmaxf(x2m + c2v[nt] - 2.f * acc[nt][r], 0.f);
      float q = __builtin_amdgcn_rcpf(1.f + d2);
      acc[nt][r] = q;
      s += q;
    }
    #pragma unroll
    for (int msk = 1; msk < 32; msk <<= 1) s += __shfl_xor(s, msk, 64);
    srow[r] = s;
  }

  // epilogue scratch overlaid on Abuf (dead after the final K-loop barrier)
  float* part   = &Abuf[0][0];      // [4][BM]
  float* rowinv = &Abuf[0][4 * BM];

  if (l31 == 0) {
    #pragma unroll
    for (int r = 0; r < 16; ++r)
      part[wn * BM + wm * 32 + (r & 3) + 8 * (r >> 2) + 4 * h] = srow[r];
  }
  __syncthreads();
  if (tid < BM)
    rowinv[tid] = __builtin_amdgcn_rcpf(part[tid] + part[BM + tid] +
                                        part[2 * BM + tid] + part[3 * BM + tid]);
  __syncthreads();

  // ---- normalize + coalesced stores ----
  #pragma unroll
  for (int r = 0; r < 16; ++r) {
    const int row = wm * 32 + (r & 3) + 8 * (r >> 2) + 4 * h;
    const float iv = rowinv[row];
    float* o = out + (size_t)(row0 + row) * KC + wn * 128 + l31;
    #pragma unroll
    for (int nt = 0; nt < 4; ++nt)
      o[nt * 32] = acc[nt][r] * iv;
  }
}

extern "C" void kernel_launch(void* const* d_in, const int* in_sizes, int n_in,
                              void* d_out, int out_size, void* d_ws, size_t ws_size,
                              hipStream_t stream) {
  const float* X = (const float*)d_in[0];   // inputs  [131072, 512] fp32
  const float* C = (const float*)d_in[1];   // clusters [512, 512] fp32
  float* out = (float*)d_out;               // [131072, 512] fp32

  short* Bp = (short*)d_ws;                                   // 512 KB packed bf16 clusters
  float* c2 = (float*)((char*)d_ws + (size_t)KC * DIM * 2);   // 2 KB cluster norms

  dec_pack<<<KC, 64, 0, stream>>>(C, Bp, c2);
  dec_main<<<NPTS / BM, 512, 0, stream>>>(X, Bp, c2, out);
}

// Round 11
// 172.256 us; speedup vs baseline: 1.7663x; 1.3228x over previous
//
#include <hip/hip_runtime.h>
#include <hip/hip_bf16.h>
#include <stdint.h>

#define NPTS 131072
#define DIM  512
#define KC   512
#define BM   64
#define BK   32
#define NKT  16          // DIM / BK

typedef float f32x16 __attribute__((ext_vector_type(16)));
typedef float f32x4  __attribute__((ext_vector_type(4)));
typedef short bf16x8 __attribute__((ext_vector_type(8)));

__device__ __forceinline__ float sq4(f32x4 a) {
  return a.x*a.x + a.y*a.y + a.z*a.z + a.w*a.w;
}

// packed RNE fp32->bf16 (v_cvt_pk_bf16_f32)
__device__ __forceinline__ bf16x8 pack8c(f32x4 a, f32x4 b) {
  union { __hip_bfloat162 h; short s[2]; } u0, u1, u2, u3;
  u0.h = __float22bfloat162_rn(make_float2(a.x, a.y));
  u1.h = __float22bfloat162_rn(make_float2(a.z, a.w));
  u2.h = __float22bfloat162_rn(make_float2(b.x, b.y));
  u3.h = __float22bfloat162_rn(make_float2(b.z, b.w));
  bf16x8 r;
  r[0] = u0.s[0]; r[1] = u0.s[1]; r[2] = u1.s[0]; r[3] = u1.s[1];
  r[4] = u2.s[0]; r[5] = u2.s[1]; r[6] = u3.s[0]; r[7] = u3.s[1];
  return r;
}

// scalar RNE (cluster pre-kernel only)
__device__ __forceinline__ short f2bf(float f) {
  union { float f; unsigned u; } v; v.f = f;
  unsigned r = v.u + 0x7FFFu + ((v.u >> 16) & 1u);
  return (short)(r >> 16);
}
__device__ __forceinline__ bf16x8 pack8(f32x4 a, f32x4 b) {
  bf16x8 p;
  p[0] = f2bf(a.x); p[1] = f2bf(a.y); p[2] = f2bf(a.z); p[3] = f2bf(a.w);
  p[4] = f2bf(b.x); p[5] = f2bf(b.y); p[6] = f2bf(b.z); p[7] = f2bf(b.w);
  return p;
}

__device__ __forceinline__ void gload_lds16(const void* g, void* l) {
  __builtin_amdgcn_global_load_lds(
      (const __attribute__((address_space(1))) unsigned int*)g,
      (__attribute__((address_space(3))) unsigned int*)l, 16, 0, 0);
}

// ---------------------------------------------------------------------------
// Cluster pre-kernel (layout verified R5-R10): fp32 [512][512] -> bf16 in
// MFMA-B-fragment order. Short offset = q*8192 + wn*2048 + nt*512 +
// (h*32+r)*8 where q = kt*2+st is the HALF-KT index — each 16 KB half-tile
// is contiguous, staged linearly by the main kernel, fragments read at
// base + lane*16 (conflict-free). c2[n] = ||c_n||^2 fp32.
// ---------------------------------------------------------------------------
__global__ void dec_pack(const float* __restrict__ C, short* __restrict__ Bp,
                         float* __restrict__ c2) {
  const int n    = blockIdx.x;
  const int lane = threadIdx.x;
  const float* src = C + (size_t)n * DIM + lane * 8;
  f32x4 v0 = *(const f32x4*)src;
  f32x4 v1 = *(const f32x4*)(src + 4);
  float s = sq4(v0) + sq4(v1);
  #pragma unroll
  for (int m = 1; m < 64; m <<= 1) s += __shfl_xor(s, m, 64);
  if (lane == 0) c2[n] = s;
  const int kt = lane >> 2;
  const int st = (lane >> 1) & 1;
  const int hh = lane & 1;
  const int wn = n >> 7, nt = (n >> 5) & 3, r = n & 31;
  const size_t slot =
      (((size_t)(kt * 2 + st) * 4 + wn) * 4 + nt) * 64 + hh * 32 + r;
  *(bf16x8*)(Bp + slot * 8) = pack8(v0, v1);
}

// ---------------------------------------------------------------------------
// Main fused kernel (R11): counted-vmcnt raw-barrier phase schedule.
// 512 threads = 8 waves (wm = wave>>2, wn = wave&3); block tile 64 x 512.
// Wave tile 32x128; 4 MFMA per phase, 2 phases (s = 0,1) per kt.
//
// 32 phases. Phase p body:  [s_waitcnt vmcnt(N); s_barrier]  ->
//   [stage: even p: B-half(p+2) 2x gload_lds + A(kt+1) 1x gload_lds;
//           odd  p: B-half(p+2) 2x gload_lds]                ->
//   [compute(kt, s=p&1): 2x ds_read_b128 fp32 A-frag (XOR-swizzled) ->
//    cvt_pk -> 4x ds_read_b128 B-frag (linear) -> 4 MFMA; x2 fused].
// N = ops staged in phase p-1 (even->2 entering odd, odd->3 entering even):
// forces phase p-2's loads (the buffers consumed NOW) while the previous
// phase's loads stay in flight — no full vmcnt drain anywhere in the loop.
// Group-count waits are order-insensitive within a phase; phase boundaries
// pinned with sched_barrier(0). All loop VMEM are global_load_lds (no
// register destinations -> no compiler-inserted vmcnt waits).
// Rings: B 3 x 16 KB (stage->use distance 2 phases, barrier-separated from
// the last reader); A fp32 2 x 8 KB (kt dbuf). LDS 64 KB -> 2 blocks/CU.
// Tail: stages continue with clamped sources (dead loads) to keep counts
// uniform; a final __syncthreads drains them before the epilogue overlay.
// ---------------------------------------------------------------------------
__global__ __launch_bounds__(512, 4)
void dec_main(const float* __restrict__ X, const short* __restrict__ Bp,
              const float* __restrict__ c2g, float* __restrict__ out) {
  __shared__ short Bh[3][8192];     // 3 x 16 KB half-kt B tiles
  __shared__ float Ab[2][2048];     // 2 x 8 KB fp32 A tiles (swizzled chunks)

  const int tid  = threadIdx.x;
  const int lane = tid & 63;
  const int wave = tid >> 6;
  const int wm   = wave >> 2;   // 0..1 : row half
  const int wn   = wave & 3;    // 0..3 : column quarter
  const int l31  = lane & 31;
  const int h    = lane >> 5;
  const int row0 = blockIdx.x * BM;

  // A staging: thread t -> row (t>>3), source chunk ((t&7)^((t>>3)&7)),
  // dest linear t*16B. (source-side XOR swizzle; gload_lds dest stays linear)
  const float* asrc = X + (size_t)(row0 + (tid >> 3)) * DIM +
                      (((tid & 7) ^ ((tid >> 3) & 7)) << 2);
  // B staging: half-tile q -> 2 x 16B/thread, linear
  const short* bsrc = Bp + tid * 8;

  // A fragment read base (floats): row (wm*32+l31)
  const int abase = (wm * 32 + l31) * BK;
  const int asw   = l31 & 7;    // read-side XOR

  f32x16 acc[4];
  #pragma unroll
  for (int nt = 0; nt < 4; ++nt) acc[nt] = (f32x16)0.f;
  float x2 = 0.f;

  // ---- prologue: stage q=0 (+A(0)), then q=1; matches steady-state counts
  gload_lds16(bsrc, &Bh[0][tid * 8]);
  gload_lds16(bsrc + 4096, &Bh[0][4096 + tid * 8]);
  gload_lds16(asrc, &Ab[0][tid * 4]);
  __builtin_amdgcn_sched_barrier(0);
  gload_lds16(bsrc + 8192, &Bh[1][tid * 8]);
  gload_lds16(bsrc + 8192 + 4096, &Bh[1][4096 + tid * 8]);
  __builtin_amdgcn_sched_barrier(0);

  int rb = 0;   // Bh ring position of (kt, s=0)
  for (int kt = 0; kt < NKT; ++kt) {
    const int rb1 = (rb == 2) ? 0 : rb + 1;   // (kt,s=1) buffer
    const int rb2 = (rb == 0) ? 2 : rb - 1;   // stage target for even phase

    // ================= even phase p = 2kt =================
    asm volatile("s_waitcnt vmcnt(2)" ::: "memory");
    __builtin_amdgcn_sched_barrier(0);
    __builtin_amdgcn_s_barrier();
    __builtin_amdgcn_sched_barrier(0);
    {
      const int q  = (2 * kt + 2 < 32) ? 2 * kt + 2 : 31;   // B half index
      const int ka = (kt + 1 < NKT) ? kt + 1 : NKT - 1;     // A tile index
      gload_lds16(bsrc + (size_t)q * 8192, &Bh[rb2][tid * 8]);
      gload_lds16(bsrc + (size_t)q * 8192 + 4096, &Bh[rb2][4096 + tid * 8]);
      gload_lds16(asrc + ka * BK, &Ab[(kt + 1) & 1][tid * 4]);
    }
    __builtin_amdgcn_sched_barrier(0);
    {
      const float* A = &Ab[kt & 1][0];
      f32x4 lo = *(const f32x4*)&A[abase + (((h * 2 + 0) ^ asw) << 2)];
      f32x4 hi = *(const f32x4*)&A[abase + (((h * 2 + 1) ^ asw) << 2)];
      x2 += sq4(lo) + sq4(hi);
      bf16x8 af = pack8c(lo, hi);
      bf16x8 bfr[4];
      #pragma unroll
      for (int nt = 0; nt < 4; ++nt)
        bfr[nt] = *(const bf16x8*)&Bh[rb][(wn * 4 + nt) * 512 + lane * 8];
      #pragma unroll
      for (int nt = 0; nt < 4; ++nt)
        acc[nt] = __builtin_amdgcn_mfma_f32_32x32x16_bf16(
            af, bfr[nt], acc[nt], 0, 0, 0);
    }

    // ================= odd phase p = 2kt+1 =================
    asm volatile("s_waitcnt vmcnt(3)" ::: "memory");
    __builtin_amdgcn_sched_barrier(0);
    __builtin_amdgcn_s_barrier();
    __builtin_amdgcn_sched_barrier(0);
    {
      const int q = (2 * kt + 3 < 32) ? 2 * kt + 3 : 31;
      gload_lds16(bsrc + (size_t)q * 8192, &Bh[rb][tid * 8]);
      gload_lds16(bsrc + (size_t)q * 8192 + 4096, &Bh[rb][4096 + tid * 8]);
    }
    __builtin_amdgcn_sched_barrier(0);
    {
      const float* A = &Ab[kt & 1][0];
      f32x4 lo = *(const f32x4*)&A[abase + (((4 + h * 2 + 0) ^ asw) << 2)];
      f32x4 hi = *(const f32x4*)&A[abase + (((4 + h * 2 + 1) ^ asw) << 2)];
      x2 += sq4(lo) + sq4(hi);
      bf16x8 af = pack8c(lo, hi);
      bf16x8 bfr[4];
      #pragma unroll
      for (int nt = 0; nt < 4; ++nt)
        bfr[nt] = *(const bf16x8*)&Bh[rb1][(wn * 4 + nt) * 512 + lane * 8];
      #pragma unroll
      for (int nt = 0; nt < 4; ++nt)
        acc[nt] = __builtin_amdgcn_mfma_f32_32x32x16_bf16(
            af, bfr[nt], acc[nt], 0, 0, 0);
    }

    rb = (rb + 2 >= 3) ? rb - 1 : rb + 2;   // (rb + 2) % 3
  }

  // drain dead tail stages before overlaying epilogue scratch on Ab
  __syncthreads();

  // ---- x2: combine the two k-halves; lane l31 holds x2(row wm*32+l31) ----
  x2 += __shfl_xor(x2, 32, 64);

  float c2v[4];
  #pragma unroll
  for (int nt = 0; nt < 4; ++nt) c2v[nt] = c2g[wn * 128 + nt * 32 + l31];

  // ---- q = rcp(1+d2), per-row partial sums over this wave's 128 cols ----
  float srow[16];
  #pragma unroll
  for (int r = 0; r < 16; ++r) {
    const int mloc = (r & 3) + 8 * (r >> 2) + 4 * h;   // 0..31
    const float x2m = __shfl(x2, mloc, 64);
    float s = 0.f;
    #pragma unroll
    for (int nt = 0; nt < 4; ++nt) {
      float d2 = fmaxf(x2m + c2v[nt] - 2.f * acc[nt][r], 0.f);
      float q = __builtin_amdgcn_rcpf(1.f + d2);
      acc[nt][r] = q;
      s += q;
    }
    #pragma unroll
    for (int msk = 1; msk < 32; msk <<= 1) s += __shfl_xor(s, msk, 64);
    srow[r] = s;
  }

  // epilogue scratch overlaid on Ab (dead after the drain barrier)
  float* part   = &Ab[0][0];        // [4][BM]
  float* rowinv = &Ab[0][4 * BM];

  if (l31 == 0) {
    #pragma unroll
    for (int r = 0; r < 16; ++r)
      part[wn * BM + wm * 32 + (r & 3) + 8 * (r >> 2) + 4 * h] = srow[r];
  }
  __syncthreads();
  if (tid < BM)
    rowinv[tid] = __builtin_amdgcn_rcpf(part[tid] + part[BM + tid] +
                                        part[2 * BM + tid] + part[3 * BM + tid]);
  __syncthreads();

  // ---- normalize + coalesced stores ----
  #pragma unroll
  for (int r = 0; r < 16; ++r) {
    const int row = wm * 32 + (r & 3) + 8 * (r >> 2) + 4 * h;
    const float iv = rowinv[row];
    float* o = out + (size_t)(row0 + row) * KC + wn * 128 + l31;
    #pragma unroll
    for (int nt = 0; nt < 4; ++nt)
      o[nt * 32] = acc[nt][r] * iv;
  }
}

extern "C" void kernel_launch(void* const* d_in, const int* in_sizes, int n_in,
                              void* d_out, int out_size, void* d_ws, size_t ws_size,
                              hipStream_t stream) {
  const float* X = (const float*)d_in[0];   // inputs  [131072, 512] fp32
  const float* C = (const float*)d_in[1];   // clusters [512, 512] fp32
  float* out = (float*)d_out;               // [131072, 512] fp32

  short* Bp = (short*)d_ws;                                   // 512 KB packed bf16 clusters
  float* c2 = (float*)((char*)d_ws + (size_t)KC * DIM * 2);   // 2 KB cluster norms

  dec_pack<<<KC, 64, 0, stream>>>(C, Bp, c2);
  dec_main<<<NPTS / BM, 512, 0, stream>>>(X, Bp, c2, out);
}